// Round 13
// baseline (53.255 us; speedup 1.0000x reference)
//
#include <hip/hip_runtime.h>
#include <hip/hip_bf16.h>

#define ENC 15

typedef __attribute__((ext_vector_type(4))) float f32x4;
typedef __attribute__((ext_vector_type(8))) short s16x8;
typedef __attribute__((ext_vector_type(4))) short s16x4;

static __device__ __forceinline__ short f2bf(float v) {
    __hip_bfloat16 h = __float2bfloat16(v);
    return __builtin_bit_cast(short, h);
}

// Wave-local LDS fence (r9-r11 proven).
#define WAVE_FENCE() do { \
    asm volatile("s_waitcnt lgkmcnt(0)" ::: "memory"); \
    __builtin_amdgcn_sched_barrier(0); \
} while (0)

// ---- weight prep (IDENTICAL to r11 — no scaling) ----
// ws (bf16):
//   W1b [128][32] @ 0     k padded 18->32
//   W2s [16384]  @ 4096   pre-swizzled: ws[4096+p] = W2[p ^ s(p)],
//                         s(p)=((p>>7)&7)<<3 (row-preserving XOR)
__global__ void NSC_prep_kernel(const float* __restrict__ W1,
                                const float* __restrict__ W2,
                                __hip_bfloat16* __restrict__ ws) {
    int t = blockIdx.x * 256 + threadIdx.x;
    if (t < 4096) {
        int row = t >> 5, k = t & 31;
        float v = (k < 18) ? W1[row * 18 + k] : 0.0f;
        ws[t] = __float2bfloat16(v);
    } else if (t < 20480) {
        int p = t - 4096;
        int l = p ^ (((p >> 7) & 7) << 3);
        ws[t] = __float2bfloat16(W2[l]);
    }
}

// One block = HALF a complex = 128 px, 4 waves, n=2 (acc2[8][2] = 64 regs).
// ONLY change vs the passing r11: tile halved for occupancy —
// LDS 48 KB -> 3 blocks/CU, launch_bounds(256,3) -> 12 waves/CU target.
// __sinf everywhere (r12's sin_rev experiment fully reverted).
// LDS map: [0,32768) W2s ; [32768,40960) slice0 (X, then h ks=1,3) ;
//          [40960,49152) slice1 (h ks=0,2).
// Arithmetic bit-identical to r11 (canary: absmax == 0.015625 exactly).
__global__ __launch_bounds__(256, 3)
void NSC_59133109732095_kernel(
    const float* __restrict__ points,
    const float* __restrict__ encodings,
    const float* __restrict__ b1,
    const float* __restrict__ b2,
    const float* __restrict__ W3,
    const float* __restrict__ b3,
    const int*   __restrict__ complexes,
    const __hip_bfloat16* __restrict__ ws,
    float* __restrict__ out0,
    float* __restrict__ out1,
    float* __restrict__ out2)
{
    __shared__ __align__(16) char smem[49152];
    char* W2s = smem;            // 32 KB pre-swizzled W2 (linear stage)
    char* Xb  = smem + 32768;    // slice0: X rows [128][64 B]

    const int blk  = blockIdx.x;
    const int c    = blk >> 1;
    const int half = blk & 1;
    const int tid  = threadIdx.x;
    const int lane = tid & 63;
    const int wv   = tid >> 6;    // wave -> local px [wv*32, wv*32+32)
    const int g    = lane >> 4;
    const int r16  = lane & 15;

    const __hip_bfloat16* W1b = ws;
    const char* ws2b = (const char*)(ws + 4096);

    // ---- stage W2s loads early (hidden under phase 0) ----
    s16x8 stg[8];
    #pragma unroll
    for (int i = 0; i < 8; ++i)
        stg[i] = *(const s16x8*)(ws2b + i * 4096 + tid * 16);

    // ---- phase 0: interp; lanes 0..31 of wave wv own local px = wv*32+lane ----
    float p[3] = {0.f, 0.f, 0.f};
    if (lane < 32) {
        const int lpx = wv * 32 + lane;          // block-local pixel
        const int px  = half * 128 + lpx;        // pixel within complex
        const int pi = px >> 4, pj = px & 15;
        const float ui = (float)pi * (1.0f / 15.0f);
        const float uj = (float)pj * (1.0f / 15.0f);
        const float w00 = (1.0f - ui) * (1.0f - uj), w01 = (1.0f - ui) * uj;
        const float w10 = ui * (1.0f - uj),          w11 = ui * uj;
        const int v0 = complexes[c * 4 + 0], v1 = complexes[c * 4 + 1];
        const int v2 = complexes[c * 4 + 2], v3 = complexes[c * 4 + 3];

        #pragma unroll
        for (int f = 0; f < 3; ++f)
            p[f] = w00 * points[v0 * 3 + f] + w01 * points[v1 * 3 + f]
                 + w10 * points[v2 * 3 + f] + w11 * points[v3 * 3 + f];

        float Xf[18];
        #pragma unroll
        for (int k = 0; k < ENC; ++k)
            Xf[k] = w00 * encodings[v0 * ENC + k] + w01 * encodings[v1 * ENC + k]
                  + w10 * encodings[v2 * ENC + k] + w11 * encodings[v3 * ENC + k];
        #pragma unroll
        for (int f = 0; f < 3; ++f) Xf[ENC + f] = __sinf(p[f]);

        #pragma unroll
        for (int ch = 0; ch < 4; ++ch) {
            s16x8 v;
            #pragma unroll
            for (int i = 0; i < 8; ++i) {
                int k = ch * 8 + i;
                v[i] = (k < 18) ? f2bf(Xf[k]) : (short)0;
            }
            *(s16x8*)(Xb + lpx * 64 + ((ch * 16) ^ ((lpx & 3) << 4))) = v;
        }
    }

    // write staged W2 chunks (linear)
    #pragma unroll
    for (int i = 0; i < 8; ++i)
        *(s16x8*)(W2s + i * 4096 + tid * 16) = stg[i];

    __syncthreads();   // W2s (block-shared) + X visible

    // ---- read X B-frags once ----
    s16x8 bx[2];
    #pragma unroll
    for (int n = 0; n < 2; ++n) {
        int px = wv * 32 + n * 16 + r16;
        bx[n] = *(const s16x8*)(Xb + px * 64 + ((g * 16) ^ ((px & 3) << 4)));
    }

    // ---- init layer-2 accumulators with biases ----
    f32x4 acc2[8][2];
    #pragma unroll
    for (int m = 0; m < 8; ++m) {
        f32x4 bv = *(const f32x4*)(b2 + m * 16 + g * 4);
        acc2[m][0] = bv; acc2[m][1] = bv;
    }

    // ---- prologue: layer-1 pair for ks=0 ----
    f32x4 accp[2][2];
    #pragma unroll
    for (int mm = 0; mm < 2; ++mm) {
        f32x4 bv = *(const f32x4*)(b1 + mm * 16 + g * 4);
        accp[mm][0] = bv; accp[mm][1] = bv;
        s16x8 a1 = *(const s16x8*)(W1b + (mm * 16 + r16) * 32 + g * 8);
        #pragma unroll
        for (int n = 0; n < 2; ++n)
            accp[mm][n] = __builtin_amdgcn_mfma_f32_16x16x32_bf16(a1, bx[n], accp[mm][n], 0, 0, 0);
    }

    // ---- main ks pipeline (double-buffered h-slices, 1 fence/ks) ----
    #pragma unroll
    for (int ks = 0; ks < 4; ++ks) {
        char* hsl = smem + 32768 + (1 - (ks & 1)) * 8192;

        // h1 slice = sin(accp) -> bf16
        s16x4 hv[2][2];
        #pragma unroll
        for (int mm = 0; mm < 2; ++mm)
            #pragma unroll
            for (int n = 0; n < 2; ++n)
                #pragma unroll
                for (int r = 0; r < 4; ++r)
                    hv[mm][n][r] = f2bf(__sinf(accp[mm][n][r]));

        #pragma unroll
        for (int mm = 0; mm < 2; ++mm)
            #pragma unroll
            for (int n = 0; n < 2; ++n) {
                int px = wv * 32 + n * 16 + r16;
                *(s16x4*)(hsl + px * 64 + ((mm * 32 + g * 8) ^ ((px & 3) << 4))) = hv[mm][n];
            }
        WAVE_FENCE();   // slice visible (wave-private rows)

        s16x8 hb[2];
        #pragma unroll
        for (int n = 0; n < 2; ++n) {
            int px = wv * 32 + n * 16 + r16;
            hb[n] = *(const s16x8*)(hsl + px * 64 + ((g * 16) ^ ((px & 3) << 4)));
        }

        // issue next L1 pair before the L2 bulk (overlap material)
        if (ks < 3) {
            #pragma unroll
            for (int mm = 0; mm < 2; ++mm) {
                int m1 = (ks + 1) * 2 + mm;
                f32x4 bv = *(const f32x4*)(b1 + m1 * 16 + g * 4);
                accp[mm][0] = bv; accp[mm][1] = bv;
                s16x8 a1 = *(const s16x8*)(W1b + (m1 * 16 + r16) * 32 + g * 8);
                #pragma unroll
                for (int n = 0; n < 2; ++n)
                    accp[mm][n] = __builtin_amdgcn_mfma_f32_16x16x32_bf16(a1, bx[n], accp[mm][n], 0, 0, 0);
            }
        }

        // layer-2 MFMAs; a2 from LDS (swizzled ds_read_b128)
        #pragma unroll
        for (int hf = 0; hf < 2; ++hf) {
            s16x8 a2[4];
            #pragma unroll
            for (int mi = 0; mi < 4; ++mi) {
                int row = (hf * 4 + mi) * 16 + r16;
                int L   = row * 256 + ks * 64 + g * 16;
                a2[mi] = *(const s16x8*)(W2s + (L ^ ((r16 & 7) << 4)));
            }
            #pragma unroll
            for (int mi = 0; mi < 4; ++mi)
                #pragma unroll
                for (int n = 0; n < 2; ++n)
                    acc2[hf * 4 + mi][n] = __builtin_amdgcn_mfma_f32_16x16x32_bf16(
                        a2[mi], hb[n], acc2[hf * 4 + mi][n], 0, 0, 0);
        }
    }

    // ---- layer 3 in registers: x[f][px] = sum_j W3[f][j]*sin(acc2_j) ----
    float pf0[2] = {0.f, 0.f};
    float pf1[2] = {0.f, 0.f};
    float pf2[2] = {0.f, 0.f};
    #pragma unroll
    for (int m = 0; m < 8; ++m) {
        float s2[2][4];
        #pragma unroll
        for (int n = 0; n < 2; ++n)
            #pragma unroll
            for (int r = 0; r < 4; ++r)
                s2[n][r] = __sinf(acc2[m][n][r]);
        f32x4 w3a = *(const f32x4*)(W3 + 0 * 128 + m * 16 + g * 4);
        f32x4 w3b = *(const f32x4*)(W3 + 1 * 128 + m * 16 + g * 4);
        f32x4 w3c = *(const f32x4*)(W3 + 2 * 128 + m * 16 + g * 4);
        #pragma unroll
        for (int n = 0; n < 2; ++n)
            #pragma unroll
            for (int r = 0; r < 4; ++r) {
                pf0[n] = fmaf(s2[n][r], w3a[r], pf0[n]);
                pf1[n] = fmaf(s2[n][r], w3b[r], pf1[n]);
                pf2[n] = fmaf(s2[n][r], w3c[r], pf2[n]);
            }
    }
    {
        const float b30 = b3[0], b31 = b3[1], b32 = b3[2];
        #pragma unroll
        for (int n = 0; n < 2; ++n) {
            float v0r = pf0[n]; v0r += __shfl_xor(v0r, 16); v0r += __shfl_xor(v0r, 32);
            float v1r = pf1[n]; v1r += __shfl_xor(v1r, 16); v1r += __shfl_xor(v1r, 32);
            float v2r = pf2[n]; v2r += __shfl_xor(v2r, 16); v2r += __shfl_xor(v2r, 32);
            if (g == n) {   // lane l = g*16+r16 (<32) owns local px = wv*32 + l
                float x0 = v0r + b30;
                float x1 = v1r + b31;
                float x2 = v2r + b32;
                const int base = (c * 256 + half * 128 + wv * 32 + n * 16 + r16) * 3;
                out0[base + 0] = p[0] + x0;
                out0[base + 1] = p[1] + x1;
                out0[base + 2] = p[2] + x2;
                out1[base + 0] = x0;
                out1[base + 1] = x1;
                out1[base + 2] = x2;
            }
        }
    }
    if (blk == 0 && tid == 0) out2[0] = 1.0f;
}

extern "C" void kernel_launch(void* const* d_in, const int* in_sizes, int n_in,
                              void* d_out, int out_size, void* d_ws, size_t ws_size,
                              hipStream_t stream) {
    const float* points    = (const float*)d_in[0];
    const float* encodings = (const float*)d_in[1];
    const float* W1        = (const float*)d_in[2];
    const float* b1        = (const float*)d_in[3];
    const float* W2        = (const float*)d_in[4];
    const float* b2        = (const float*)d_in[5];
    const float* W3        = (const float*)d_in[6];
    const float* b3        = (const float*)d_in[7];
    const int*   complexes = (const int*)d_in[8];

    const int C  = in_sizes[8] / 4;          // 2048
    const int N3 = C * 256 * 3;              // 1,572,864

    float* out0 = (float*)d_out;
    float* out1 = out0 + N3;
    float* out2 = out1 + N3;

    __hip_bfloat16* ws = (__hip_bfloat16*)d_ws;  // needs 40960 B

    NSC_prep_kernel<<<80, 256, 0, stream>>>(W1, W2, ws);
    NSC_59133109732095_kernel<<<C * 2, 256, 0, stream>>>(
        points, encodings, b1, b2, W3, b3, complexes, ws, out0, out1, out2);
}

// Round 14
// 47.708 us; speedup vs baseline: 1.1163x; 1.1163x over previous
//
#include <hip/hip_runtime.h>
#include <hip/hip_bf16.h>

#define ENC 15

typedef __attribute__((ext_vector_type(4))) float f32x4;
typedef __attribute__((ext_vector_type(8))) short s16x8;
typedef __attribute__((ext_vector_type(2))) unsigned int u32x2;

static __device__ __forceinline__ short f2bf(float v) {
    __hip_bfloat16 h = __float2bfloat16(v);
    return __builtin_bit_cast(short, h);
}

// gfx950 HW packed f32->bf16 (RNE), 2 converts in 1 VALU op (T12 recipe).
static __device__ __forceinline__ unsigned f2bf_pk(float lo, float hi) {
    unsigned r;
    asm("v_cvt_pk_bf16_f32 %0, %1, %2" : "=v"(r) : "v"(lo), "v"(hi));
    return r;
}

// Wave-local LDS fence (r9-r11 proven).
#define WAVE_FENCE() do { \
    asm volatile("s_waitcnt lgkmcnt(0)" ::: "memory"); \
    __builtin_amdgcn_sched_barrier(0); \
} while (0)

// ---- weight prep (IDENTICAL to r11) ----
// ws (bf16):
//   W1b [128][32] @ 0     k padded 18->32
//   W2s [16384]  @ 4096   pre-swizzled: ws[4096+p] = W2[p ^ s(p)],
//                         s(p)=((p>>7)&7)<<3 (row-preserving XOR)
__global__ void NSC_prep_kernel(const float* __restrict__ W1,
                                const float* __restrict__ W2,
                                __hip_bfloat16* __restrict__ ws) {
    int t = blockIdx.x * 256 + threadIdx.x;
    if (t < 4096) {
        int row = t >> 5, k = t & 31;
        float v = (k < 18) ? W1[row * 18 + k] : 0.0f;
        ws[t] = __float2bfloat16(v);
    } else if (t < 20480) {
        int p = t - 4096;
        int l = p ^ (((p >> 7) & 7) << 3);
        ws[t] = __float2bfloat16(W2[l]);
    }
}

// r11 base (one block = one complex = 256 px, 4 waves, n=4, W2 in LDS),
// with three surgical edits:
//  (1) pipeline reschedule: sin+pack+WRITE of slice ks+1 sits BETWEEN the
//      two L2 half-bulks of ks -> write latency covered by 16 MFMAs, the
//      iter-top fence drains an already-quiet queue.
//  (2) packing via v_cvt_pk_bf16_f32 (1 VALU op per 2 converts, HW RNE).
//  (3) s_setprio(1) around L2 MFMA bulks (T5; waves are phase-staggered).
// LDS map: [0,32768) W2s ; [32768,49152) slice0 (X, then h ks=1,3) ;
//          [49152,65536) slice1 (h ks=0,2).
__global__ __launch_bounds__(256, 2)
void NSC_59133109732095_kernel(
    const float* __restrict__ points,
    const float* __restrict__ encodings,
    const float* __restrict__ b1,
    const float* __restrict__ b2,
    const float* __restrict__ W3,
    const float* __restrict__ b3,
    const int*   __restrict__ complexes,
    const __hip_bfloat16* __restrict__ ws,
    float* __restrict__ out0,
    float* __restrict__ out1,
    float* __restrict__ out2)
{
    __shared__ __align__(16) char smem[65536];
    char* W2s = smem;            // 32 KB pre-swizzled W2 (linear stage)
    char* Xb  = smem + 32768;    // slice0: X rows [256][64 B]

    const int c    = blockIdx.x;
    const int tid  = threadIdx.x;
    const int lane = tid & 63;
    const int wv   = tid >> 6;
    const int g    = lane >> 4;
    const int r16  = lane & 15;

    const __hip_bfloat16* W1b = ws;
    const char* ws2b = (const char*)(ws + 4096);

    // ---- stage W2s loads early (hidden under phase 0) ----
    s16x8 stg[8];
    #pragma unroll
    for (int i = 0; i < 8; ++i)
        stg[i] = *(const s16x8*)(ws2b + i * 4096 + tid * 16);

    // ---- phase 0: per-thread bilinear interp, pixel = tid ----
    const int pi = tid >> 4, pj = tid & 15;
    const float ui = (float)pi * (1.0f / 15.0f);
    const float uj = (float)pj * (1.0f / 15.0f);
    const float w00 = (1.0f - ui) * (1.0f - uj), w01 = (1.0f - ui) * uj;
    const float w10 = ui * (1.0f - uj),          w11 = ui * uj;
    const int v0 = complexes[c * 4 + 0], v1 = complexes[c * 4 + 1];
    const int v2 = complexes[c * 4 + 2], v3 = complexes[c * 4 + 3];

    float p[3];
    #pragma unroll
    for (int f = 0; f < 3; ++f)
        p[f] = w00 * points[v0 * 3 + f] + w01 * points[v1 * 3 + f]
             + w10 * points[v2 * 3 + f] + w11 * points[v3 * 3 + f];

    float Xf[32];
    #pragma unroll
    for (int k = 0; k < ENC; ++k)
        Xf[k] = w00 * encodings[v0 * ENC + k] + w01 * encodings[v1 * ENC + k]
              + w10 * encodings[v2 * ENC + k] + w11 * encodings[v3 * ENC + k];
    #pragma unroll
    for (int f = 0; f < 3; ++f) Xf[ENC + f] = __sinf(p[f]);
    #pragma unroll
    for (int k = 18; k < 32; ++k) Xf[k] = 0.0f;

    // write X row (32 bf16) via packed converts
    #pragma unroll
    for (int ch = 0; ch < 2; ++ch) {
        u32x2 v0w, v1w;
        v0w[0] = f2bf_pk(Xf[ch * 16 + 0],  Xf[ch * 16 + 1]);
        v0w[1] = f2bf_pk(Xf[ch * 16 + 2],  Xf[ch * 16 + 3]);
        v1w[0] = f2bf_pk(Xf[ch * 16 + 4],  Xf[ch * 16 + 5]);
        v1w[1] = f2bf_pk(Xf[ch * 16 + 6],  Xf[ch * 16 + 7]);
        u32x2 v2w, v3w;
        v2w[0] = f2bf_pk(Xf[ch * 16 + 8],  Xf[ch * 16 + 9]);
        v2w[1] = f2bf_pk(Xf[ch * 16 + 10], Xf[ch * 16 + 11]);
        v3w[0] = f2bf_pk(Xf[ch * 16 + 12], Xf[ch * 16 + 13]);
        v3w[1] = f2bf_pk(Xf[ch * 16 + 14], Xf[ch * 16 + 15]);
        char* base0 = Xb + tid * 64 + (((ch * 2 + 0) * 16) ^ ((tid & 3) << 4));
        char* base1 = Xb + tid * 64 + (((ch * 2 + 1) * 16) ^ ((tid & 3) << 4));
        *(u32x2*)(base0 + 0) = v0w;
        *(u32x2*)(base0 + 8) = v1w;
        *(u32x2*)(base1 + 0) = v2w;
        *(u32x2*)(base1 + 8) = v3w;
    }

    // write staged W2 chunks (linear)
    #pragma unroll
    for (int i = 0; i < 8; ++i)
        *(s16x8*)(W2s + i * 4096 + tid * 16) = stg[i];

    __syncthreads();   // W2s (block-shared) + X visible

    // ---- read X B-frags once ----
    s16x8 bx[4];
    #pragma unroll
    for (int n = 0; n < 4; ++n) {
        int px = wv * 64 + n * 16 + r16;
        bx[n] = *(const s16x8*)(Xb + px * 64 + ((g * 16) ^ ((px & 3) << 4)));
    }

    // ---- init layer-2 accumulators with biases ----
    f32x4 acc2[8][4];
    #pragma unroll
    for (int m = 0; m < 8; ++m) {
        f32x4 bv = *(const f32x4*)(b2 + m * 16 + g * 4);
        #pragma unroll
        for (int n = 0; n < 4; ++n) acc2[m][n] = bv;
    }

    // ---- prologue: L1 pair ks=0, then sin+pack+write buf(0)=slice1 ----
    f32x4 accp[2][4];
    #pragma unroll
    for (int mm = 0; mm < 2; ++mm) {
        f32x4 bv = *(const f32x4*)(b1 + mm * 16 + g * 4);
        #pragma unroll
        for (int n = 0; n < 4; ++n) accp[mm][n] = bv;
        s16x8 a1 = *(const s16x8*)(W1b + (mm * 16 + r16) * 32 + g * 8);
        #pragma unroll
        for (int n = 0; n < 4; ++n)
            accp[mm][n] = __builtin_amdgcn_mfma_f32_16x16x32_bf16(a1, bx[n], accp[mm][n], 0, 0, 0);
    }
    {
        char* hsl = smem + 49152;   // buf(0) = slice1
        #pragma unroll
        for (int mm = 0; mm < 2; ++mm)
            #pragma unroll
            for (int n = 0; n < 4; ++n) {
                u32x2 hw;
                hw[0] = f2bf_pk(__sinf(accp[mm][n][0]), __sinf(accp[mm][n][1]));
                hw[1] = f2bf_pk(__sinf(accp[mm][n][2]), __sinf(accp[mm][n][3]));
                int px = wv * 64 + n * 16 + r16;
                *(u32x2*)(hsl + px * 64 + ((mm * 32 + g * 8) ^ ((px & 3) << 4))) = hw;
            }
    }

    // ---- main ks pipeline ----
    #pragma unroll
    for (int ks = 0; ks < 4; ++ks) {
        char* cur = smem + 32768 + (1 - (ks & 1)) * 16384;        // buf(ks)
        char* nxt = smem + 32768 + (ks & 1) * 16384;              // buf(ks+1)

        WAVE_FENCE();   // drains writes of buf(ks) (+ old reads); wave-private

        s16x8 hb[4];
        #pragma unroll
        for (int n = 0; n < 4; ++n) {
            int px = wv * 64 + n * 16 + r16;
            hb[n] = *(const s16x8*)(cur + px * 64 + ((g * 16) ^ ((px & 3) << 4)));
        }

        // L1 MFMA for ks+1 (independent of hb; covers hb latency)
        if (ks < 3) {
            #pragma unroll
            for (int mm = 0; mm < 2; ++mm) {
                int m1 = (ks + 1) * 2 + mm;
                f32x4 bv = *(const f32x4*)(b1 + m1 * 16 + g * 4);
                #pragma unroll
                for (int n = 0; n < 4; ++n) accp[mm][n] = bv;
                s16x8 a1 = *(const s16x8*)(W1b + (m1 * 16 + r16) * 32 + g * 8);
                #pragma unroll
                for (int n = 0; n < 4; ++n)
                    accp[mm][n] = __builtin_amdgcn_mfma_f32_16x16x32_bf16(a1, bx[n], accp[mm][n], 0, 0, 0);
            }
        }

        // L2 half-bulk hf=0
        __builtin_amdgcn_s_setprio(1);
        {
            s16x8 a2[4];
            #pragma unroll
            for (int mi = 0; mi < 4; ++mi) {
                int row = mi * 16 + r16;
                int L   = row * 256 + ks * 64 + g * 16;
                a2[mi] = *(const s16x8*)(W2s + (L ^ ((r16 & 7) << 4)));
            }
            #pragma unroll
            for (int mi = 0; mi < 4; ++mi)
                #pragma unroll
                for (int n = 0; n < 4; ++n)
                    acc2[mi][n] = __builtin_amdgcn_mfma_f32_16x16x32_bf16(
                        a2[mi], hb[n], acc2[mi][n], 0, 0, 0);
        }
        __builtin_amdgcn_s_setprio(0);

        // sin+pack+write slice ks+1 (write latency covered by hf=1's MFMAs)
        if (ks < 3) {
            #pragma unroll
            for (int mm = 0; mm < 2; ++mm)
                #pragma unroll
                for (int n = 0; n < 4; ++n) {
                    u32x2 hw;
                    hw[0] = f2bf_pk(__sinf(accp[mm][n][0]), __sinf(accp[mm][n][1]));
                    hw[1] = f2bf_pk(__sinf(accp[mm][n][2]), __sinf(accp[mm][n][3]));
                    int px = wv * 64 + n * 16 + r16;
                    *(u32x2*)(nxt + px * 64 + ((mm * 32 + g * 8) ^ ((px & 3) << 4))) = hw;
                }
        }

        // L2 half-bulk hf=1
        __builtin_amdgcn_s_setprio(1);
        {
            s16x8 a2[4];
            #pragma unroll
            for (int mi = 0; mi < 4; ++mi) {
                int row = (4 + mi) * 16 + r16;
                int L   = row * 256 + ks * 64 + g * 16;
                a2[mi] = *(const s16x8*)(W2s + (L ^ ((r16 & 7) << 4)));
            }
            #pragma unroll
            for (int mi = 0; mi < 4; ++mi)
                #pragma unroll
                for (int n = 0; n < 4; ++n)
                    acc2[4 + mi][n] = __builtin_amdgcn_mfma_f32_16x16x32_bf16(
                        a2[mi], hb[n], acc2[4 + mi][n], 0, 0, 0);
        }
        __builtin_amdgcn_s_setprio(0);
    }

    // ---- layer 3 in registers (r11-identical) ----
    float pf0[4] = {0.f, 0.f, 0.f, 0.f};
    float pf1[4] = {0.f, 0.f, 0.f, 0.f};
    float pf2[4] = {0.f, 0.f, 0.f, 0.f};
    #pragma unroll
    for (int m = 0; m < 8; ++m) {
        float s2[4][4];
        #pragma unroll
        for (int n = 0; n < 4; ++n)
            #pragma unroll
            for (int r = 0; r < 4; ++r)
                s2[n][r] = __sinf(acc2[m][n][r]);
        f32x4 w3a = *(const f32x4*)(W3 + 0 * 128 + m * 16 + g * 4);
        f32x4 w3b = *(const f32x4*)(W3 + 1 * 128 + m * 16 + g * 4);
        f32x4 w3c = *(const f32x4*)(W3 + 2 * 128 + m * 16 + g * 4);
        #pragma unroll
        for (int n = 0; n < 4; ++n)
            #pragma unroll
            for (int r = 0; r < 4; ++r) {
                pf0[n] = fmaf(s2[n][r], w3a[r], pf0[n]);
                pf1[n] = fmaf(s2[n][r], w3b[r], pf1[n]);
                pf2[n] = fmaf(s2[n][r], w3c[r], pf2[n]);
            }
    }
    {
        const float b30 = b3[0], b31 = b3[1], b32 = b3[2];
        #pragma unroll
        for (int n = 0; n < 4; ++n) {
            float v0r = pf0[n]; v0r += __shfl_xor(v0r, 16); v0r += __shfl_xor(v0r, 32);
            float v1r = pf1[n]; v1r += __shfl_xor(v1r, 16); v1r += __shfl_xor(v1r, 32);
            float v2r = pf2[n]; v2r += __shfl_xor(v2r, 16); v2r += __shfl_xor(v2r, 32);
            if (g == n) {
                float x0 = v0r + b30;
                float x1 = v1r + b31;
                float x2 = v2r + b32;
                const int base = (c * 256 + tid) * 3;
                out0[base + 0] = p[0] + x0;
                out0[base + 1] = p[1] + x1;
                out0[base + 2] = p[2] + x2;
                out1[base + 0] = x0;
                out1[base + 1] = x1;
                out1[base + 2] = x2;
            }
        }
    }
    if (c == 0 && tid == 0) out2[0] = 1.0f;
}

extern "C" void kernel_launch(void* const* d_in, const int* in_sizes, int n_in,
                              void* d_out, int out_size, void* d_ws, size_t ws_size,
                              hipStream_t stream) {
    const float* points    = (const float*)d_in[0];
    const float* encodings = (const float*)d_in[1];
    const float* W1        = (const float*)d_in[2];
    const float* b1        = (const float*)d_in[3];
    const float* W2        = (const float*)d_in[4];
    const float* b2        = (const float*)d_in[5];
    const float* W3        = (const float*)d_in[6];
    const float* b3        = (const float*)d_in[7];
    const int*   complexes = (const int*)d_in[8];

    const int C  = in_sizes[8] / 4;          // 2048
    const int N3 = C * 256 * 3;              // 1,572,864

    float* out0 = (float*)d_out;
    float* out1 = out0 + N3;
    float* out2 = out1 + N3;

    __hip_bfloat16* ws = (__hip_bfloat16*)d_ws;  // needs 40960 B

    NSC_prep_kernel<<<80, 256, 0, stream>>>(W1, W2, ws);
    NSC_59133109732095_kernel<<<C, 256, 0, stream>>>(
        points, encodings, b1, b2, W3, b3, complexes, ws, out0, out1, out2);
}

// Round 15
// 45.500 us; speedup vs baseline: 1.1704x; 1.0485x over previous
//
#include <hip/hip_runtime.h>
#include <hip/hip_bf16.h>

#define ENC 15

typedef __attribute__((ext_vector_type(4))) float f32x4;
typedef __attribute__((ext_vector_type(8))) short s16x8;
typedef __attribute__((ext_vector_type(4))) short s16x4;

static __device__ __forceinline__ short f2bf(float v) {
    __hip_bfloat16 h = __float2bfloat16(v);
    return __builtin_bit_cast(short, h);
}

// Wave-local LDS fence (r9-r11 proven).
#define WAVE_FENCE() do { \
    asm volatile("s_waitcnt lgkmcnt(0)" ::: "memory"); \
    __builtin_amdgcn_sched_barrier(0); \
} while (0)

// ---- weight prep (IDENTICAL to r11) ----
// ws (bf16):
//   W1b [128][32] @ 0     k padded 18->32
//   W2s [16384]  @ 4096   pre-swizzled: ws[4096+p] = W2[p ^ s(p)],
//                         s(p)=((p>>7)&7)<<3 (row-preserving XOR)
__global__ void NSC_prep_kernel(const float* __restrict__ W1,
                                const float* __restrict__ W2,
                                __hip_bfloat16* __restrict__ ws) {
    int t = blockIdx.x * 256 + threadIdx.x;
    if (t < 4096) {
        int row = t >> 5, k = t & 31;
        float v = (k < 18) ? W1[row * 18 + k] : 0.0f;
        ws[t] = __float2bfloat16(v);
    } else if (t < 20480) {
        int p = t - 4096;
        int l = p ^ (((p >> 7) & 7) << 3);
        ws[t] = __float2bfloat16(W2[l]);
    }
}

// r11 base (one block = one complex = 256 px, 4 waves, n=4, W2 in LDS,
// ks-pipeline, layer 3 in registers) with ONE surgical change:
//   slice swizzle mask (px&3)<<4  ->  ((px>>1)&3)<<4  on all four access
//   sites (X write, bx read, h write, hb read). The old mask was correlated
//   with row-parity -> only 4 distinct banks per 16-lane g-group (4-way
//   conflict, 5.1M conflict-cycles/dispatch). New mask spreads to 8 banks
//   (2-way = free, m136). Same XOR involution both sides -> data identical.
// LDS map: [0,32768) W2s ; [32768,49152) slice0 (X, then h ks=1,3) ;
//          [49152,65536) slice1 (h ks=0,2).
// Canary: absmax == 0.015625 exactly.
__global__ __launch_bounds__(256, 2)
void NSC_59133109732095_kernel(
    const float* __restrict__ points,
    const float* __restrict__ encodings,
    const float* __restrict__ b1,
    const float* __restrict__ b2,
    const float* __restrict__ W3,
    const float* __restrict__ b3,
    const int*   __restrict__ complexes,
    const __hip_bfloat16* __restrict__ ws,
    float* __restrict__ out0,
    float* __restrict__ out1,
    float* __restrict__ out2)
{
    __shared__ __align__(16) char smem[65536];
    char* W2s = smem;            // 32 KB pre-swizzled W2 (linear stage)
    char* Xb  = smem + 32768;    // slice0: X rows [256][64 B]

    const int c    = blockIdx.x;
    const int tid  = threadIdx.x;
    const int lane = tid & 63;
    const int wv   = tid >> 6;
    const int g    = lane >> 4;
    const int r16  = lane & 15;

    const __hip_bfloat16* W1b = ws;
    const char* ws2b = (const char*)(ws + 4096);

    // ---- stage W2s loads early (hidden under phase 0) ----
    s16x8 stg[8];
    #pragma unroll
    for (int i = 0; i < 8; ++i)
        stg[i] = *(const s16x8*)(ws2b + i * 4096 + tid * 16);

    // ---- phase 0: per-thread bilinear interp, pixel = tid ----
    const int pi = tid >> 4, pj = tid & 15;
    const float ui = (float)pi * (1.0f / 15.0f);
    const float uj = (float)pj * (1.0f / 15.0f);
    const float w00 = (1.0f - ui) * (1.0f - uj), w01 = (1.0f - ui) * uj;
    const float w10 = ui * (1.0f - uj),          w11 = ui * uj;
    const int v0 = complexes[c * 4 + 0], v1 = complexes[c * 4 + 1];
    const int v2 = complexes[c * 4 + 2], v3 = complexes[c * 4 + 3];

    float p[3];
    #pragma unroll
    for (int f = 0; f < 3; ++f)
        p[f] = w00 * points[v0 * 3 + f] + w01 * points[v1 * 3 + f]
             + w10 * points[v2 * 3 + f] + w11 * points[v3 * 3 + f];

    float Xf[18];
    #pragma unroll
    for (int k = 0; k < ENC; ++k)
        Xf[k] = w00 * encodings[v0 * ENC + k] + w01 * encodings[v1 * ENC + k]
              + w10 * encodings[v2 * ENC + k] + w11 * encodings[v3 * ENC + k];
    #pragma unroll
    for (int f = 0; f < 3; ++f) Xf[ENC + f] = __sinf(p[f]);

    // write X row (32 bf16 zero-padded), new 8-bank swizzle
    #pragma unroll
    for (int ch = 0; ch < 4; ++ch) {
        s16x8 v;
        #pragma unroll
        for (int i = 0; i < 8; ++i) {
            int k = ch * 8 + i;
            v[i] = (k < 18) ? f2bf(Xf[k]) : (short)0;
        }
        *(s16x8*)(Xb + tid * 64 + ((ch * 16) ^ (((tid >> 1) & 3) << 4))) = v;
    }

    // write staged W2 chunks (linear)
    #pragma unroll
    for (int i = 0; i < 8; ++i)
        *(s16x8*)(W2s + i * 4096 + tid * 16) = stg[i];

    __syncthreads();   // W2s (block-shared) + X visible

    // ---- read X B-frags once ----
    s16x8 bx[4];
    #pragma unroll
    for (int n = 0; n < 4; ++n) {
        int px = wv * 64 + n * 16 + r16;
        bx[n] = *(const s16x8*)(Xb + px * 64 + ((g * 16) ^ (((px >> 1) & 3) << 4)));
    }

    // ---- init layer-2 accumulators with biases ----
    f32x4 acc2[8][4];
    #pragma unroll
    for (int m = 0; m < 8; ++m) {
        f32x4 bv = *(const f32x4*)(b2 + m * 16 + g * 4);
        #pragma unroll
        for (int n = 0; n < 4; ++n) acc2[m][n] = bv;
    }

    // ---- prologue: layer-1 pair for ks=0 ----
    f32x4 accp[2][4];
    #pragma unroll
    for (int mm = 0; mm < 2; ++mm) {
        f32x4 bv = *(const f32x4*)(b1 + mm * 16 + g * 4);
        #pragma unroll
        for (int n = 0; n < 4; ++n) accp[mm][n] = bv;
        s16x8 a1 = *(const s16x8*)(W1b + (mm * 16 + r16) * 32 + g * 8);
        #pragma unroll
        for (int n = 0; n < 4; ++n)
            accp[mm][n] = __builtin_amdgcn_mfma_f32_16x16x32_bf16(a1, bx[n], accp[mm][n], 0, 0, 0);
    }

    // ---- main ks pipeline (double-buffered h-slices, 1 fence/ks) ----
    #pragma unroll
    for (int ks = 0; ks < 4; ++ks) {
        char* hsl = smem + 32768 + (1 - (ks & 1)) * 16384;

        // h1 slice = sin(accp) -> bf16
        s16x4 hv[2][4];
        #pragma unroll
        for (int mm = 0; mm < 2; ++mm)
            #pragma unroll
            for (int n = 0; n < 4; ++n)
                #pragma unroll
                for (int r = 0; r < 4; ++r)
                    hv[mm][n][r] = f2bf(__sinf(accp[mm][n][r]));

        #pragma unroll
        for (int mm = 0; mm < 2; ++mm)
            #pragma unroll
            for (int n = 0; n < 4; ++n) {
                int px = wv * 64 + n * 16 + r16;
                *(s16x4*)(hsl + px * 64 + ((mm * 32 + g * 8) ^ (((px >> 1) & 3) << 4))) = hv[mm][n];
            }
        WAVE_FENCE();   // slice visible (wave-private rows)

        s16x8 hb[4];
        #pragma unroll
        for (int n = 0; n < 4; ++n) {
            int px = wv * 64 + n * 16 + r16;
            hb[n] = *(const s16x8*)(hsl + px * 64 + ((g * 16) ^ (((px >> 1) & 3) << 4)));
        }

        // issue next L1 pair before the L2 bulk (overlap material)
        if (ks < 3) {
            #pragma unroll
            for (int mm = 0; mm < 2; ++mm) {
                int m1 = (ks + 1) * 2 + mm;
                f32x4 bv = *(const f32x4*)(b1 + m1 * 16 + g * 4);
                #pragma unroll
                for (int n = 0; n < 4; ++n) accp[mm][n] = bv;
                s16x8 a1 = *(const s16x8*)(W1b + (m1 * 16 + r16) * 32 + g * 8);
                #pragma unroll
                for (int n = 0; n < 4; ++n)
                    accp[mm][n] = __builtin_amdgcn_mfma_f32_16x16x32_bf16(a1, bx[n], accp[mm][n], 0, 0, 0);
            }
        }

        // layer-2 MFMAs; a2 from LDS (swizzled ds_read_b128, unchanged)
        #pragma unroll
        for (int hf = 0; hf < 2; ++hf) {
            s16x8 a2[4];
            #pragma unroll
            for (int mi = 0; mi < 4; ++mi) {
                int row = (hf * 4 + mi) * 16 + r16;
                int L   = row * 256 + ks * 64 + g * 16;
                a2[mi] = *(const s16x8*)(W2s + (L ^ ((r16 & 7) << 4)));
            }
            #pragma unroll
            for (int mi = 0; mi < 4; ++mi)
                #pragma unroll
                for (int n = 0; n < 4; ++n)
                    acc2[hf * 4 + mi][n] = __builtin_amdgcn_mfma_f32_16x16x32_bf16(
                        a2[mi], hb[n], acc2[hf * 4 + mi][n], 0, 0, 0);
        }
    }

    // ---- layer 3 in registers (r11-identical) ----
    float pf0[4] = {0.f, 0.f, 0.f, 0.f};
    float pf1[4] = {0.f, 0.f, 0.f, 0.f};
    float pf2[4] = {0.f, 0.f, 0.f, 0.f};
    #pragma unroll
    for (int m = 0; m < 8; ++m) {
        float s2[4][4];
        #pragma unroll
        for (int n = 0; n < 4; ++n)
            #pragma unroll
            for (int r = 0; r < 4; ++r)
                s2[n][r] = __sinf(acc2[m][n][r]);
        f32x4 w3a = *(const f32x4*)(W3 + 0 * 128 + m * 16 + g * 4);
        f32x4 w3b = *(const f32x4*)(W3 + 1 * 128 + m * 16 + g * 4);
        f32x4 w3c = *(const f32x4*)(W3 + 2 * 128 + m * 16 + g * 4);
        #pragma unroll
        for (int n = 0; n < 4; ++n)
            #pragma unroll
            for (int r = 0; r < 4; ++r) {
                pf0[n] = fmaf(s2[n][r], w3a[r], pf0[n]);
                pf1[n] = fmaf(s2[n][r], w3b[r], pf1[n]);
                pf2[n] = fmaf(s2[n][r], w3c[r], pf2[n]);
            }
    }
    {
        const float b30 = b3[0], b31 = b3[1], b32 = b3[2];
        #pragma unroll
        for (int n = 0; n < 4; ++n) {
            float v0r = pf0[n]; v0r += __shfl_xor(v0r, 16); v0r += __shfl_xor(v0r, 32);
            float v1r = pf1[n]; v1r += __shfl_xor(v1r, 16); v1r += __shfl_xor(v1r, 32);
            float v2r = pf2[n]; v2r += __shfl_xor(v2r, 16); v2r += __shfl_xor(v2r, 32);
            if (g == n) {
                float x0 = v0r + b30;
                float x1 = v1r + b31;
                float x2 = v2r + b32;
                const int base = (c * 256 + tid) * 3;
                out0[base + 0] = p[0] + x0;
                out0[base + 1] = p[1] + x1;
                out0[base + 2] = p[2] + x2;
                out1[base + 0] = x0;
                out1[base + 1] = x1;
                out1[base + 2] = x2;
            }
        }
    }
    if (c == 0 && tid == 0) out2[0] = 1.0f;
}

extern "C" void kernel_launch(void* const* d_in, const int* in_sizes, int n_in,
                              void* d_out, int out_size, void* d_ws, size_t ws_size,
                              hipStream_t stream) {
    const float* points    = (const float*)d_in[0];
    const float* encodings = (const float*)d_in[1];
    const float* W1        = (const float*)d_in[2];
    const float* b1        = (const float*)d_in[3];
    const float* W2        = (const float*)d_in[4];
    const float* b2        = (const float*)d_in[5];
    const float* W3        = (const float*)d_in[6];
    const float* b3        = (const float*)d_in[7];
    const int*   complexes = (const int*)d_in[8];

    const int C  = in_sizes[8] / 4;          // 2048
    const int N3 = C * 256 * 3;              // 1,572,864

    float* out0 = (float*)d_out;
    float* out1 = out0 + N3;
    float* out2 = out1 + N3;

    __hip_bfloat16* ws = (__hip_bfloat16*)d_ws;  // needs 40960 B

    NSC_prep_kernel<<<80, 256, 0, stream>>>(W1, W2, ws);
    NSC_59133109732095_kernel<<<C, 256, 0, stream>>>(
        points, encodings, b1, b2, W3, b3, complexes, ws, out0, out1, out2);
}

// Round 16
// 45.398 us; speedup vs baseline: 1.1731x; 1.0022x over previous
//
#include <hip/hip_runtime.h>
#include <hip/hip_bf16.h>

#define ENC 15

typedef __attribute__((ext_vector_type(4))) float f32x4;
typedef __attribute__((ext_vector_type(8))) short s16x8;
typedef __attribute__((ext_vector_type(4))) short s16x4;

static __device__ __forceinline__ short f2bf(float v) {
    __hip_bfloat16 h = __float2bfloat16(v);
    return __builtin_bit_cast(short, h);
}

// Compiler-only ordering (r16 change): the h-slice write->read is SAME-WAVE,
// SAME-ADDRESS; the DS pipe executes a wave's LDS ops in order, so LDS
// memory RAW needs no runtime lgkmcnt drain — only compiler ordering across
// the aliased Xb/Hb phases. The compiler still emits fine-grained
// lgkmcnt(N) before MFMAs that consume ds_read results.
#define WAVE_ORDER() do { \
    asm volatile("" ::: "memory"); \
    __builtin_amdgcn_sched_barrier(0); \
} while (0)

// ---- weight prep (IDENTICAL to r11/r15) ----
// ws (bf16):
//   W1b [128][32] @ 0     k padded 18->32
//   W2s [16384]  @ 4096   pre-swizzled: ws[4096+p] = W2[p ^ s(p)],
//                         s(p)=((p>>7)&7)<<3 (row-preserving XOR)
__global__ void NSC_prep_kernel(const float* __restrict__ W1,
                                const float* __restrict__ W2,
                                __hip_bfloat16* __restrict__ ws) {
    int t = blockIdx.x * 256 + threadIdx.x;
    if (t < 4096) {
        int row = t >> 5, k = t & 31;
        float v = (k < 18) ? W1[row * 18 + k] : 0.0f;
        ws[t] = __float2bfloat16(v);
    } else if (t < 20480) {
        int p = t - 4096;
        int l = p ^ (((p >> 7) & 7) << 3);
        ws[t] = __float2bfloat16(W2[l]);
    }
}

// r15 base (one block = one complex = 256 px, 4 waves, n=4, W2 in LDS,
// ks-pipeline, 8-bank slice swizzle ((px>>1)&3)<<4, layer 3 in registers)
// with ONE order-only change: the per-ks runtime lgkmcnt(0) drain is
// replaced by a compiler-only barrier (WAVE_ORDER). Data layout and
// arithmetic bit-identical to r15 (canary: absmax == 0.015625 exactly).
// LDS map: [0,32768) W2s ; [32768,49152) slice0 (X, then h ks=1,3) ;
//          [49152,65536) slice1 (h ks=0,2).
__global__ __launch_bounds__(256, 2)
void NSC_59133109732095_kernel(
    const float* __restrict__ points,
    const float* __restrict__ encodings,
    const float* __restrict__ b1,
    const float* __restrict__ b2,
    const float* __restrict__ W3,
    const float* __restrict__ b3,
    const int*   __restrict__ complexes,
    const __hip_bfloat16* __restrict__ ws,
    float* __restrict__ out0,
    float* __restrict__ out1,
    float* __restrict__ out2)
{
    __shared__ __align__(16) char smem[65536];
    char* W2s = smem;            // 32 KB pre-swizzled W2 (linear stage)
    char* Xb  = smem + 32768;    // slice0: X rows [256][64 B]

    const int c    = blockIdx.x;
    const int tid  = threadIdx.x;
    const int lane = tid & 63;
    const int wv   = tid >> 6;
    const int g    = lane >> 4;
    const int r16  = lane & 15;

    const __hip_bfloat16* W1b = ws;
    const char* ws2b = (const char*)(ws + 4096);

    // ---- stage W2s loads early (hidden under phase 0) ----
    s16x8 stg[8];
    #pragma unroll
    for (int i = 0; i < 8; ++i)
        stg[i] = *(const s16x8*)(ws2b + i * 4096 + tid * 16);

    // ---- phase 0: per-thread bilinear interp, pixel = tid ----
    const int pi = tid >> 4, pj = tid & 15;
    const float ui = (float)pi * (1.0f / 15.0f);
    const float uj = (float)pj * (1.0f / 15.0f);
    const float w00 = (1.0f - ui) * (1.0f - uj), w01 = (1.0f - ui) * uj;
    const float w10 = ui * (1.0f - uj),          w11 = ui * uj;
    const int v0 = complexes[c * 4 + 0], v1 = complexes[c * 4 + 1];
    const int v2 = complexes[c * 4 + 2], v3 = complexes[c * 4 + 3];

    float p[3];
    #pragma unroll
    for (int f = 0; f < 3; ++f)
        p[f] = w00 * points[v0 * 3 + f] + w01 * points[v1 * 3 + f]
             + w10 * points[v2 * 3 + f] + w11 * points[v3 * 3 + f];

    float Xf[18];
    #pragma unroll
    for (int k = 0; k < ENC; ++k)
        Xf[k] = w00 * encodings[v0 * ENC + k] + w01 * encodings[v1 * ENC + k]
              + w10 * encodings[v2 * ENC + k] + w11 * encodings[v3 * ENC + k];
    #pragma unroll
    for (int f = 0; f < 3; ++f) Xf[ENC + f] = __sinf(p[f]);

    // write X row (32 bf16 zero-padded), 8-bank swizzle
    #pragma unroll
    for (int ch = 0; ch < 4; ++ch) {
        s16x8 v;
        #pragma unroll
        for (int i = 0; i < 8; ++i) {
            int k = ch * 8 + i;
            v[i] = (k < 18) ? f2bf(Xf[k]) : (short)0;
        }
        *(s16x8*)(Xb + tid * 64 + ((ch * 16) ^ (((tid >> 1) & 3) << 4))) = v;
    }

    // write staged W2 chunks (linear)
    #pragma unroll
    for (int i = 0; i < 8; ++i)
        *(s16x8*)(W2s + i * 4096 + tid * 16) = stg[i];

    __syncthreads();   // W2s (block-shared) + X visible

    // ---- read X B-frags once ----
    s16x8 bx[4];
    #pragma unroll
    for (int n = 0; n < 4; ++n) {
        int px = wv * 64 + n * 16 + r16;
        bx[n] = *(const s16x8*)(Xb + px * 64 + ((g * 16) ^ (((px >> 1) & 3) << 4)));
    }

    // ---- init layer-2 accumulators with biases ----
    f32x4 acc2[8][4];
    #pragma unroll
    for (int m = 0; m < 8; ++m) {
        f32x4 bv = *(const f32x4*)(b2 + m * 16 + g * 4);
        #pragma unroll
        for (int n = 0; n < 4; ++n) acc2[m][n] = bv;
    }

    // ---- prologue: layer-1 pair for ks=0 ----
    f32x4 accp[2][4];
    #pragma unroll
    for (int mm = 0; mm < 2; ++mm) {
        f32x4 bv = *(const f32x4*)(b1 + mm * 16 + g * 4);
        #pragma unroll
        for (int n = 0; n < 4; ++n) accp[mm][n] = bv;
        s16x8 a1 = *(const s16x8*)(W1b + (mm * 16 + r16) * 32 + g * 8);
        #pragma unroll
        for (int n = 0; n < 4; ++n)
            accp[mm][n] = __builtin_amdgcn_mfma_f32_16x16x32_bf16(a1, bx[n], accp[mm][n], 0, 0, 0);
    }

    // ---- main ks pipeline (double-buffered h-slices, compiler-only order) ----
    #pragma unroll
    for (int ks = 0; ks < 4; ++ks) {
        char* hsl = smem + 32768 + (1 - (ks & 1)) * 16384;

        // h1 slice = sin(accp) -> bf16
        s16x4 hv[2][4];
        #pragma unroll
        for (int mm = 0; mm < 2; ++mm)
            #pragma unroll
            for (int n = 0; n < 4; ++n)
                #pragma unroll
                for (int r = 0; r < 4; ++r)
                    hv[mm][n][r] = f2bf(__sinf(accp[mm][n][r]));

        #pragma unroll
        for (int mm = 0; mm < 2; ++mm)
            #pragma unroll
            for (int n = 0; n < 4; ++n) {
                int px = wv * 64 + n * 16 + r16;
                *(s16x4*)(hsl + px * 64 + ((mm * 32 + g * 8) ^ (((px >> 1) & 3) << 4))) = hv[mm][n];
            }
        WAVE_ORDER();   // same-wave DS RAW is in-order; compiler ordering only

        s16x8 hb[4];
        #pragma unroll
        for (int n = 0; n < 4; ++n) {
            int px = wv * 64 + n * 16 + r16;
            hb[n] = *(const s16x8*)(hsl + px * 64 + ((g * 16) ^ (((px >> 1) & 3) << 4)));
        }

        // issue next L1 pair before the L2 bulk (overlap material)
        if (ks < 3) {
            #pragma unroll
            for (int mm = 0; mm < 2; ++mm) {
                int m1 = (ks + 1) * 2 + mm;
                f32x4 bv = *(const f32x4*)(b1 + m1 * 16 + g * 4);
                #pragma unroll
                for (int n = 0; n < 4; ++n) accp[mm][n] = bv;
                s16x8 a1 = *(const s16x8*)(W1b + (m1 * 16 + r16) * 32 + g * 8);
                #pragma unroll
                for (int n = 0; n < 4; ++n)
                    accp[mm][n] = __builtin_amdgcn_mfma_f32_16x16x32_bf16(a1, bx[n], accp[mm][n], 0, 0, 0);
            }
        }

        // layer-2 MFMAs; a2 from LDS (swizzled ds_read_b128)
        #pragma unroll
        for (int hf = 0; hf < 2; ++hf) {
            s16x8 a2[4];
            #pragma unroll
            for (int mi = 0; mi < 4; ++mi) {
                int row = (hf * 4 + mi) * 16 + r16;
                int L   = row * 256 + ks * 64 + g * 16;
                a2[mi] = *(const s16x8*)(W2s + (L ^ ((r16 & 7) << 4)));
            }
            #pragma unroll
            for (int mi = 0; mi < 4; ++mi)
                #pragma unroll
                for (int n = 0; n < 4; ++n)
                    acc2[hf * 4 + mi][n] = __builtin_amdgcn_mfma_f32_16x16x32_bf16(
                        a2[mi], hb[n], acc2[hf * 4 + mi][n], 0, 0, 0);
        }
    }

    // ---- layer 3 in registers (r11-identical) ----
    float pf0[4] = {0.f, 0.f, 0.f, 0.f};
    float pf1[4] = {0.f, 0.f, 0.f, 0.f};
    float pf2[4] = {0.f, 0.f, 0.f, 0.f};
    #pragma unroll
    for (int m = 0; m < 8; ++m) {
        float s2[4][4];
        #pragma unroll
        for (int n = 0; n < 4; ++n)
            #pragma unroll
            for (int r = 0; r < 4; ++r)
                s2[n][r] = __sinf(acc2[m][n][r]);
        f32x4 w3a = *(const f32x4*)(W3 + 0 * 128 + m * 16 + g * 4);
        f32x4 w3b = *(const f32x4*)(W3 + 1 * 128 + m * 16 + g * 4);
        f32x4 w3c = *(const f32x4*)(W3 + 2 * 128 + m * 16 + g * 4);
        #pragma unroll
        for (int n = 0; n < 4; ++n)
            #pragma unroll
            for (int r = 0; r < 4; ++r) {
                pf0[n] = fmaf(s2[n][r], w3a[r], pf0[n]);
                pf1[n] = fmaf(s2[n][r], w3b[r], pf1[n]);
                pf2[n] = fmaf(s2[n][r], w3c[r], pf2[n]);
            }
    }
    {
        const float b30 = b3[0], b31 = b3[1], b32 = b3[2];
        #pragma unroll
        for (int n = 0; n < 4; ++n) {
            float v0r = pf0[n]; v0r += __shfl_xor(v0r, 16); v0r += __shfl_xor(v0r, 32);
            float v1r = pf1[n]; v1r += __shfl_xor(v1r, 16); v1r += __shfl_xor(v1r, 32);
            float v2r = pf2[n]; v2r += __shfl_xor(v2r, 16); v2r += __shfl_xor(v2r, 32);
            if (g == n) {
                float x0 = v0r + b30;
                float x1 = v1r + b31;
                float x2 = v2r + b32;
                const int base = (c * 256 + tid) * 3;
                out0[base + 0] = p[0] + x0;
                out0[base + 1] = p[1] + x1;
                out0[base + 2] = p[2] + x2;
                out1[base + 0] = x0;
                out1[base + 1] = x1;
                out1[base + 2] = x2;
            }
        }
    }
    if (c == 0 && tid == 0) out2[0] = 1.0f;
}

extern "C" void kernel_launch(void* const* d_in, const int* in_sizes, int n_in,
                              void* d_out, int out_size, void* d_ws, size_t ws_size,
                              hipStream_t stream) {
    const float* points    = (const float*)d_in[0];
    const float* encodings = (const float*)d_in[1];
    const float* W1        = (const float*)d_in[2];
    const float* b1        = (const float*)d_in[3];
    const float* W2        = (const float*)d_in[4];
    const float* b2        = (const float*)d_in[5];
    const float* W3        = (const float*)d_in[6];
    const float* b3        = (const float*)d_in[7];
    const int*   complexes = (const int*)d_in[8];

    const int C  = in_sizes[8] / 4;          // 2048
    const int N3 = C * 256 * 3;              // 1,572,864

    float* out0 = (float*)d_out;
    float* out1 = out0 + N3;
    float* out2 = out1 + N3;

    __hip_bfloat16* ws = (__hip_bfloat16*)d_ws;  // needs 40960 B

    NSC_prep_kernel<<<80, 256, 0, stream>>>(W1, W2, ws);
    NSC_59133109732095_kernel<<<C, 256, 0, stream>>>(
        points, encodings, b1, b2, W3, b3, complexes, ws, out0, out1, out2);
}

// Round 17
// 44.669 us; speedup vs baseline: 1.1922x; 1.0163x over previous
//
#include <hip/hip_runtime.h>
#include <hip/hip_bf16.h>

#define ENC 15
#define INV2PI 0.15915494309189535f

typedef __attribute__((ext_vector_type(4))) float f32x4;
typedef __attribute__((ext_vector_type(8))) short s16x8;
typedef __attribute__((ext_vector_type(4))) short s16x4;

static __device__ __forceinline__ short f2bf(float v) {
    __hip_bfloat16 h = __float2bfloat16(v);
    return __builtin_bit_cast(short, h);
}

// Activation sin on PRE-SCALED accumulators: acc already carries the 1/2pi
// factor (folded into W1/W2/b1/b2), so one v_sin_f32 suffices. Using the
// compiler-visible intrinsic (NOT inline asm) so the CDNA4 trans-op
// use-hazard is handled by the compiler — r12's raw-asm version raced.
static __device__ __forceinline__ float sin_act(float x) {
    return __builtin_amdgcn_sinf(x);
}

// Compiler-only ordering (r16-proven): same-wave DS RAW is in-order.
#define WAVE_ORDER() do { \
    asm volatile("" ::: "memory"); \
    __builtin_amdgcn_sched_barrier(0); \
} while (0)

// ---- weight prep ----
// ws (bf16):
//   W1b [128][32] @ 0     = bf16(W1 * INV2PI), k padded 18->32
//   W2s [16384]  @ 4096   = bf16(W2[p ^ s(p)] * INV2PI), s(p)=((p>>7)&7)<<3
//                           (pre-swizzled so linear LDS stage + XOR read = W2)
__global__ void NSC_prep_kernel(const float* __restrict__ W1,
                                const float* __restrict__ W2,
                                __hip_bfloat16* __restrict__ ws) {
    int t = blockIdx.x * 256 + threadIdx.x;
    if (t < 4096) {
        int row = t >> 5, k = t & 31;
        float v = (k < 18) ? W1[row * 18 + k] * INV2PI : 0.0f;
        ws[t] = __float2bfloat16(v);
    } else if (t < 20480) {
        int p = t - 4096;
        int l = p ^ (((p >> 7) & 7) << 3);
        ws[t] = __float2bfloat16(W2[l] * INV2PI);
    }
}

// r16 base (one block = one complex = 256 px, 4 waves, n=4, W2 in LDS,
// ks-pipeline, 8-bank slice swizzle, compiler-only fences, layer 3 in
// registers) with ONE change: 1/2pi folded into W1/W2/b1/b2 so the 256
// activation sins are a single v_sin each (via __builtin_amdgcn_sinf)
// instead of v_mul+v_sin. Phase-0's 3 sins on unscaled p keep __sinf.
// LDS map: [0,32768) W2s ; [32768,49152) slice0 (X, then h ks=1,3) ;
//          [49152,65536) slice1 (h ks=0,2).
__global__ __launch_bounds__(256, 2)
void NSC_59133109732095_kernel(
    const float* __restrict__ points,
    const float* __restrict__ encodings,
    const float* __restrict__ b1,
    const float* __restrict__ b2,
    const float* __restrict__ W3,
    const float* __restrict__ b3,
    const int*   __restrict__ complexes,
    const __hip_bfloat16* __restrict__ ws,
    float* __restrict__ out0,
    float* __restrict__ out1,
    float* __restrict__ out2)
{
    __shared__ __align__(16) char smem[65536];
    char* W2s = smem;            // 32 KB pre-swizzled W2 (linear stage)
    char* Xb  = smem + 32768;    // slice0: X rows [256][64 B]

    const int c    = blockIdx.x;
    const int tid  = threadIdx.x;
    const int lane = tid & 63;
    const int wv   = tid >> 6;
    const int g    = lane >> 4;
    const int r16  = lane & 15;

    const __hip_bfloat16* W1b = ws;
    const char* ws2b = (const char*)(ws + 4096);

    // ---- stage W2s loads early (hidden under phase 0) ----
    s16x8 stg[8];
    #pragma unroll
    for (int i = 0; i < 8; ++i)
        stg[i] = *(const s16x8*)(ws2b + i * 4096 + tid * 16);

    // ---- phase 0: per-thread bilinear interp, pixel = tid ----
    const int pi = tid >> 4, pj = tid & 15;
    const float ui = (float)pi * (1.0f / 15.0f);
    const float uj = (float)pj * (1.0f / 15.0f);
    const float w00 = (1.0f - ui) * (1.0f - uj), w01 = (1.0f - ui) * uj;
    const float w10 = ui * (1.0f - uj),          w11 = ui * uj;
    const int v0 = complexes[c * 4 + 0], v1 = complexes[c * 4 + 1];
    const int v2 = complexes[c * 4 + 2], v3 = complexes[c * 4 + 3];

    float p[3];
    #pragma unroll
    for (int f = 0; f < 3; ++f)
        p[f] = w00 * points[v0 * 3 + f] + w01 * points[v1 * 3 + f]
             + w10 * points[v2 * 3 + f] + w11 * points[v3 * 3 + f];

    float Xf[18];
    #pragma unroll
    for (int k = 0; k < ENC; ++k)
        Xf[k] = w00 * encodings[v0 * ENC + k] + w01 * encodings[v1 * ENC + k]
              + w10 * encodings[v2 * ENC + k] + w11 * encodings[v3 * ENC + k];
    #pragma unroll
    for (int f = 0; f < 3; ++f) Xf[ENC + f] = __sinf(p[f]);   // unscaled input

    // write X row (32 bf16 zero-padded), 8-bank swizzle
    #pragma unroll
    for (int ch = 0; ch < 4; ++ch) {
        s16x8 v;
        #pragma unroll
        for (int i = 0; i < 8; ++i) {
            int k = ch * 8 + i;
            v[i] = (k < 18) ? f2bf(Xf[k]) : (short)0;
        }
        *(s16x8*)(Xb + tid * 64 + ((ch * 16) ^ (((tid >> 1) & 3) << 4))) = v;
    }

    // write staged W2 chunks (linear)
    #pragma unroll
    for (int i = 0; i < 8; ++i)
        *(s16x8*)(W2s + i * 4096 + tid * 16) = stg[i];

    __syncthreads();   // W2s (block-shared) + X visible

    // ---- read X B-frags once ----
    s16x8 bx[4];
    #pragma unroll
    for (int n = 0; n < 4; ++n) {
        int px = wv * 64 + n * 16 + r16;
        bx[n] = *(const s16x8*)(Xb + px * 64 + ((g * 16) ^ (((px >> 1) & 3) << 4)));
    }

    // ---- init layer-2 accumulators with scaled biases ----
    f32x4 acc2[8][4];
    #pragma unroll
    for (int m = 0; m < 8; ++m) {
        f32x4 bv = *(const f32x4*)(b2 + m * 16 + g * 4);
        #pragma unroll
        for (int r = 0; r < 4; ++r) bv[r] *= INV2PI;
        #pragma unroll
        for (int n = 0; n < 4; ++n) acc2[m][n] = bv;
    }

    // ---- prologue: layer-1 pair for ks=0 ----
    f32x4 accp[2][4];
    #pragma unroll
    for (int mm = 0; mm < 2; ++mm) {
        f32x4 bv = *(const f32x4*)(b1 + mm * 16 + g * 4);
        #pragma unroll
        for (int r = 0; r < 4; ++r) bv[r] *= INV2PI;
        #pragma unroll
        for (int n = 0; n < 4; ++n) accp[mm][n] = bv;
        s16x8 a1 = *(const s16x8*)(W1b + (mm * 16 + r16) * 32 + g * 8);
        #pragma unroll
        for (int n = 0; n < 4; ++n)
            accp[mm][n] = __builtin_amdgcn_mfma_f32_16x16x32_bf16(a1, bx[n], accp[mm][n], 0, 0, 0);
    }

    // ---- main ks pipeline (double-buffered h-slices, compiler-only order) ----
    #pragma unroll
    for (int ks = 0; ks < 4; ++ks) {
        char* hsl = smem + 32768 + (1 - (ks & 1)) * 16384;

        // h1 slice = sin_act(accp) -> bf16  (accp carries 1/2pi)
        s16x4 hv[2][4];
        #pragma unroll
        for (int mm = 0; mm < 2; ++mm)
            #pragma unroll
            for (int n = 0; n < 4; ++n)
                #pragma unroll
                for (int r = 0; r < 4; ++r)
                    hv[mm][n][r] = f2bf(sin_act(accp[mm][n][r]));

        #pragma unroll
        for (int mm = 0; mm < 2; ++mm)
            #pragma unroll
            for (int n = 0; n < 4; ++n) {
                int px = wv * 64 + n * 16 + r16;
                *(s16x4*)(hsl + px * 64 + ((mm * 32 + g * 8) ^ (((px >> 1) & 3) << 4))) = hv[mm][n];
            }
        WAVE_ORDER();   // same-wave DS RAW is in-order; compiler ordering only

        s16x8 hb[4];
        #pragma unroll
        for (int n = 0; n < 4; ++n) {
            int px = wv * 64 + n * 16 + r16;
            hb[n] = *(const s16x8*)(hsl + px * 64 + ((g * 16) ^ (((px >> 1) & 3) << 4)));
        }

        // issue next L1 pair before the L2 bulk (overlap material)
        if (ks < 3) {
            #pragma unroll
            for (int mm = 0; mm < 2; ++mm) {
                int m1 = (ks + 1) * 2 + mm;
                f32x4 bv = *(const f32x4*)(b1 + m1 * 16 + g * 4);
                #pragma unroll
                for (int r = 0; r < 4; ++r) bv[r] *= INV2PI;
                #pragma unroll
                for (int n = 0; n < 4; ++n) accp[mm][n] = bv;
                s16x8 a1 = *(const s16x8*)(W1b + (m1 * 16 + r16) * 32 + g * 8);
                #pragma unroll
                for (int n = 0; n < 4; ++n)
                    accp[mm][n] = __builtin_amdgcn_mfma_f32_16x16x32_bf16(a1, bx[n], accp[mm][n], 0, 0, 0);
            }
        }

        // layer-2 MFMAs; a2 from LDS (swizzled ds_read_b128)
        #pragma unroll
        for (int hf = 0; hf < 2; ++hf) {
            s16x8 a2[4];
            #pragma unroll
            for (int mi = 0; mi < 4; ++mi) {
                int row = (hf * 4 + mi) * 16 + r16;
                int L   = row * 256 + ks * 64 + g * 16;
                a2[mi] = *(const s16x8*)(W2s + (L ^ ((r16 & 7) << 4)));
            }
            #pragma unroll
            for (int mi = 0; mi < 4; ++mi)
                #pragma unroll
                for (int n = 0; n < 4; ++n)
                    acc2[hf * 4 + mi][n] = __builtin_amdgcn_mfma_f32_16x16x32_bf16(
                        a2[mi], hb[n], acc2[hf * 4 + mi][n], 0, 0, 0);
        }
    }

    // ---- layer 3 in registers: x[f][px] = sum_j W3[f][j]*sin_act(acc2_j) ----
    float pf0[4] = {0.f, 0.f, 0.f, 0.f};
    float pf1[4] = {0.f, 0.f, 0.f, 0.f};
    float pf2[4] = {0.f, 0.f, 0.f, 0.f};
    #pragma unroll
    for (int m = 0; m < 8; ++m) {
        float s2[4][4];
        #pragma unroll
        for (int n = 0; n < 4; ++n)
            #pragma unroll
            for (int r = 0; r < 4; ++r)
                s2[n][r] = sin_act(acc2[m][n][r]);   // acc2 carries 1/2pi
        f32x4 w3a = *(const f32x4*)(W3 + 0 * 128 + m * 16 + g * 4);
        f32x4 w3b = *(const f32x4*)(W3 + 1 * 128 + m * 16 + g * 4);
        f32x4 w3c = *(const f32x4*)(W3 + 2 * 128 + m * 16 + g * 4);
        #pragma unroll
        for (int n = 0; n < 4; ++n)
            #pragma unroll
            for (int r = 0; r < 4; ++r) {
                pf0[n] = fmaf(s2[n][r], w3a[r], pf0[n]);
                pf1[n] = fmaf(s2[n][r], w3b[r], pf1[n]);
                pf2[n] = fmaf(s2[n][r], w3c[r], pf2[n]);
            }
    }
    {
        const float b30 = b3[0], b31 = b3[1], b32 = b3[2];
        #pragma unroll
        for (int n = 0; n < 4; ++n) {
            float v0r = pf0[n]; v0r += __shfl_xor(v0r, 16); v0r += __shfl_xor(v0r, 32);
            float v1r = pf1[n]; v1r += __shfl_xor(v1r, 16); v1r += __shfl_xor(v1r, 32);
            float v2r = pf2[n]; v2r += __shfl_xor(v2r, 16); v2r += __shfl_xor(v2r, 32);
            if (g == n) {
                float x0 = v0r + b30;
                float x1 = v1r + b31;
                float x2 = v2r + b32;
                const int base = (c * 256 + tid) * 3;
                out0[base + 0] = p[0] + x0;
                out0[base + 1] = p[1] + x1;
                out0[base + 2] = p[2] + x2;
                out1[base + 0] = x0;
                out1[base + 1] = x1;
                out1[base + 2] = x2;
            }
        }
    }
    if (c == 0 && tid == 0) out2[0] = 1.0f;
}

extern "C" void kernel_launch(void* const* d_in, const int* in_sizes, int n_in,
                              void* d_out, int out_size, void* d_ws, size_t ws_size,
                              hipStream_t stream) {
    const float* points    = (const float*)d_in[0];
    const float* encodings = (const float*)d_in[1];
    const float* W1        = (const float*)d_in[2];
    const float* b1        = (const float*)d_in[3];
    const float* W2        = (const float*)d_in[4];
    const float* b2        = (const float*)d_in[5];
    const float* W3        = (const float*)d_in[6];
    const float* b3        = (const float*)d_in[7];
    const int*   complexes = (const int*)d_in[8];

    const int C  = in_sizes[8] / 4;          // 2048
    const int N3 = C * 256 * 3;              // 1,572,864

    float* out0 = (float*)d_out;
    float* out1 = out0 + N3;
    float* out2 = out1 + N3;

    __hip_bfloat16* ws = (__hip_bfloat16*)d_ws;  // needs 40960 B

    NSC_prep_kernel<<<80, 256, 0, stream>>>(W1, W2, ws);
    NSC_59133109732095_kernel<<<C, 256, 0, stream>>>(
        points, encodings, b1, b2, W3, b3, complexes, ws, out0, out1, out2);
}